// Round 2
// baseline (2632.317 us; speedup 1.0000x reference)
//
#include <hip/hip_runtime.h>

#define T_STEPS 8192
#define DIN     2048
#define DH      2048
#define DTOT    4096
#define QG      8
#define NQQ     32

// angle/2 in revolutions: (dot + b) / (4*pi)
#define INV4PI  0.0795774715459476678f
#define L2E     1.4426950408889634f

#if __has_builtin(__builtin_amdgcn_cosf)
#define COS_REV(x) __builtin_amdgcn_cosf(x)          // cos(2*pi*x)
#else
#define COS_REV(x) __cosf((x) * 6.28318530717958648f)
#endif

#if __has_builtin(__builtin_amdgcn_exp2f)
#define EXP2F(x) __builtin_amdgcn_exp2f(x)
#else
#define EXP2F(x) exp2f(x)
#endif

#if __has_builtin(__builtin_amdgcn_rcpf)
#define RCPF(x) __builtin_amdgcn_rcpf(x)
#else
#define RCPF(x) (1.0f / (x))
#endif

// DPP multiply-combine: x *= value_from_dpp_ctrl(x). Only involution ctrls
// (quad_perm xor patterns) are used -> direction-convention safe.
#define DPP_MUL(x, ctrl)                                                        \
  ((x) * __int_as_float(__builtin_amdgcn_update_dpp(                            \
             __float_as_int(x), __float_as_int(x), (ctrl), 0xF, 0xF, false)))

#define READLANE_F(v, l)                                                        \
  __int_as_float(__builtin_amdgcn_readlane(__float_as_int(v), (l)))

// ---------------------------------------------------------------------------
// Kernel 1: A[t][qq] = (x_t . W_gate[q, :DIN] + b_gate[q]) * INV4PI
// One block per row t; 4 waves, wave w handles gate w's 8 q outputs.
// ---------------------------------------------------------------------------
__global__ __launch_bounds__(256) void gemm_kernel(
    const float* __restrict__ x,
    const float* __restrict__ Wf, const float* __restrict__ Wi,
    const float* __restrict__ Wu, const float* __restrict__ Wo,
    const float* __restrict__ bf, const float* __restrict__ bi,
    const float* __restrict__ bu, const float* __restrict__ bo,
    float* __restrict__ A) {
  __shared__ float4 xs[DIN / 4];
  const int t   = blockIdx.x;
  const int tid = threadIdx.x;

  const float4* xrow = (const float4*)(x + (size_t)t * DIN);
  xs[tid]       = xrow[tid];
  xs[tid + 256] = xrow[tid + 256];
  __syncthreads();

  const int wave = tid >> 6;
  const int lane = tid & 63;
  const float* W  = (wave == 0) ? Wf : (wave == 1) ? Wi : (wave == 2) ? Wu : Wo;
  const float* bg = (wave == 0) ? bf : (wave == 1) ? bi : (wave == 2) ? bu : bo;

  for (int q = 0; q < QG; ++q) {
    const float4* wrow = (const float4*)(W + (size_t)q * DTOT);
    float acc = 0.f;
#pragma unroll
    for (int j = 0; j < 8; ++j) {
      float4 w4 = wrow[lane + 64 * j];
      float4 x4 = xs[lane + 64 * j];
      acc = fmaf(w4.x, x4.x, acc);
      acc = fmaf(w4.y, x4.y, acc);
      acc = fmaf(w4.z, x4.z, acc);
      acc = fmaf(w4.w, x4.w, acc);
    }
#pragma unroll
    for (int off = 32; off > 0; off >>= 1) acc += __shfl_xor(acc, off);
    if (lane == 0) A[(size_t)t * NQQ + wave * QG + q] = (acc + bg[q]) * INV4PI;
  }
}

// ---------------------------------------------------------------------------
// Kernel 2: S[qq] = sum_d W_gate[q, DIN + d] * INV4PI   (hidden-part row sums)
// 32 blocks of 1 wave; block b -> gate b>>3, q b&7.
// ---------------------------------------------------------------------------
__global__ __launch_bounds__(64) void rowsum_kernel(
    const float* __restrict__ Wf, const float* __restrict__ Wi,
    const float* __restrict__ Wu, const float* __restrict__ Wo,
    float* __restrict__ S) {
  const int b    = blockIdx.x;
  const int gate = b >> 3;
  const int q    = b & 7;
  const int lane = threadIdx.x;
  const float* W = (gate == 0) ? Wf : (gate == 1) ? Wi : (gate == 2) ? Wu : Wo;
  const float4* row = (const float4*)(W + (size_t)q * DTOT + DIN);
  float acc = 0.f;
#pragma unroll
  for (int j = 0; j < 8; ++j) {
    float4 w4 = row[lane + 64 * j];
    acc += w4.x + w4.y + w4.z + w4.w;
  }
#pragma unroll
  for (int off = 32; off > 0; off >>= 1) acc += __shfl_xor(acc, off);
  if (lane == 0) S[b] = acc * INV4PI;
}

// ---------------------------------------------------------------------------
// Kernel 3: the serial scan. One wave, 16 active lanes.
// Lane L (L<16): gate = L>>2 (0=forget,1=input,2=update,3=output),
// owns TWO angles qq = 2L, 2L+1 (within-gate q = 2*(L&3), 2*(L&3)+1).
// Per-lane partial product (c1*c2)^2, then quad_perm xor1 + xor2 (involutions,
// direction-safe) -> every lane of quad g holds P_g = prod of its 8 cos^2.
// v_readlane from lanes 0/4/8/12 -> uniform scalar gates; c,h uniform.
// ---------------------------------------------------------------------------
__global__ __launch_bounds__(64) void scan_kernel(
    const float* __restrict__ A, const float* __restrict__ S,
    float* __restrict__ hbuf, float* __restrict__ cfin) {
  const int lane = threadIdx.x;
  const bool act = lane < 16;
  const float2* A2 = (const float2*)A;   // A2[t*16 + L] = angles {2L, 2L+1} at step t
  const float2* S2 = (const float2*)S;
  const float2 Sv = act ? S2[lane] : make_float2(0.f, 0.f);
  const bool isTanh = (lane >= 8 && lane < 12);
  // gate = a1 * rcp(1 + exp2(fma(P, ka, kb))) + a2
  const float ka = isTanh ? (-4.f * L2E) : (-2.f * L2E);
  const float kb = isTanh ? (2.f * L2E) : (L2E);
  const float a1 = isTanh ? 2.f : 1.f;
  const float a2 = isTanh ? -1.f : 0.f;

  float h = 0.f, c = 0.f;
  float2 A0 = act ? A2[lane] : make_float2(0.f, 0.f);
  float2 A1 = act ? A2[16 + lane] : make_float2(0.f, 0.f);

  for (int t = 0; t < T_STEPS; ++t) {
    const float2 Acur = A0;
    A0 = A1;
    const int tp = (t + 2 < T_STEPS) ? (t + 2) : (T_STEPS - 1);
    A1 = act ? A2[(size_t)tp * 16 + lane] : make_float2(0.f, 0.f);  // prefetch

    const float ang1 = fmaf(h, Sv.x, Acur.x);  // theta/2 in revolutions
    const float ang2 = fmaf(h, Sv.y, Acur.y);
    const float c1 = COS_REV(ang1);            // parallel transcendentals
    const float c2 = COS_REV(ang2);
    float p = c1 * c2;
    p = p * p;                                 // cos^2(a)*cos^2(b)
    p = DPP_MUL(p, 0xB1);                      // quad_perm(1,0,3,2): xor 1
    p = DPP_MUL(p, 0x4E);                      // quad_perm(2,3,0,1): xor 2

    const float e  = EXP2F(fmaf(p, ka, kb));
    const float r  = RCPF(1.f + e);
    const float gv = fmaf(a1, r, a2);          // sigma(2P-1) or tanh(2P-1)

    const float f_ = READLANE_F(gv, 0);
    const float i_ = READLANE_F(gv, 4);
    const float g_ = READLANE_F(gv, 8);
    const float o_ = READLANE_F(gv, 12);

    c = fmaf(f_, c, i_ * g_);
    const float e2 = EXP2F(c * (-2.f * L2E));
    const float th = fmaf(2.f, RCPF(1.f + e2), -1.f);  // tanh(c)
    h = o_ * th;

    if (lane == 0) hbuf[t] = h;
  }
  if (lane == 0) cfin[0] = c;
}

// ---------------------------------------------------------------------------
// Kernel 4: broadcast h_t over DH, plus hx / cx tails.
// Blocks 0..8191 -> stacked rows; 8192 -> hx; 8193 -> cx.
// ---------------------------------------------------------------------------
__global__ __launch_bounds__(256) void bcast_kernel(
    const float* __restrict__ hbuf, const float* __restrict__ cfin,
    float* __restrict__ out) {
  const int b = blockIdx.x;
  float v;
  size_t off;
  if (b < T_STEPS) {
    v = hbuf[b];
    off = (size_t)b * DH;
  } else if (b == T_STEPS) {
    v = hbuf[T_STEPS - 1];
    off = (size_t)T_STEPS * DH;
  } else {
    v = cfin[0];
    off = (size_t)T_STEPS * DH + DH;
  }
  const float4 v4 = make_float4(v, v, v, v);
  float4* dst = (float4*)(out + off);
  dst[threadIdx.x]       = v4;
  dst[threadIdx.x + 256] = v4;
}

extern "C" void kernel_launch(void* const* d_in, const int* in_sizes, int n_in,
                              void* d_out, int out_size, void* d_ws, size_t ws_size,
                              hipStream_t stream) {
  const float* x  = (const float*)d_in[0];
  const float* Wf = (const float*)d_in[1];
  const float* bf = (const float*)d_in[2];
  const float* Wi = (const float*)d_in[3];
  const float* bi = (const float*)d_in[4];
  const float* Wu = (const float*)d_in[5];
  const float* bu = (const float*)d_in[6];
  const float* Wo = (const float*)d_in[7];
  const float* bo = (const float*)d_in[8];
  float* out = (float*)d_out;

  // workspace layout (floats): A[8192*32] | S[32] | hbuf[8192] | cfin[1]
  float* A    = (float*)d_ws;
  float* S    = A + (size_t)T_STEPS * NQQ;
  float* hbuf = S + NQQ;
  float* cfin = hbuf + T_STEPS;

  hipLaunchKernelGGL(gemm_kernel, dim3(T_STEPS), dim3(256), 0, stream,
                     x, Wf, Wi, Wu, Wo, bf, bi, bu, bo, A);
  hipLaunchKernelGGL(rowsum_kernel, dim3(NQQ), dim3(64), 0, stream,
                     Wf, Wi, Wu, Wo, S);
  hipLaunchKernelGGL(scan_kernel, dim3(1), dim3(64), 0, stream,
                     A, S, hbuf, cfin);
  hipLaunchKernelGGL(bcast_kernel, dim3(T_STEPS + 2), dim3(256), 0, stream,
                     hbuf, cfin, out);
}

// Round 3
// 1191.641 us; speedup vs baseline: 2.2090x; 2.2090x over previous
//
#include <hip/hip_runtime.h>

#define T_STEPS 8192
#define DIN     2048
#define DH      2048
#define DTOT    4096
#define QG      8
#define NQQ     32

// angle/2 in revolutions: (dot + b) / (4*pi)
#define INV4PI  0.0795774715459476678f
#define L2E     1.4426950408889634f

#if __has_builtin(__builtin_amdgcn_cosf)
#define COS_REV(x) __builtin_amdgcn_cosf(x)          // cos(2*pi*x)
#else
#define COS_REV(x) __cosf((x) * 6.28318530717958648f)
#endif

#if __has_builtin(__builtin_amdgcn_exp2f)
#define EXP2F(x) __builtin_amdgcn_exp2f(x)
#else
#define EXP2F(x) exp2f(x)
#endif

#if __has_builtin(__builtin_amdgcn_rcpf)
#define RCPF(x) __builtin_amdgcn_rcpf(x)
#else
#define RCPF(x) (1.0f / (x))
#endif

// DPP multiply-combine: x *= value_from_dpp_ctrl(x). Only involution ctrls
// (quad_perm xor patterns) are used -> direction-convention safe.
#define DPP_MUL(x, ctrl)                                                        \
  ((x) * __int_as_float(__builtin_amdgcn_update_dpp(                            \
             __float_as_int(x), __float_as_int(x), (ctrl), 0xF, 0xF, false)))

#define READLANE_F(v, l)                                                        \
  __int_as_float(__builtin_amdgcn_readlane(__float_as_int(v), (l)))

// ---------------------------------------------------------------------------
// Kernel 1: A[t][qq] = (x_t . W_gate[q, :DIN] + b_gate[q]) * INV4PI
// One block per row t; 4 waves, wave w handles gate w's 8 q outputs.
// ---------------------------------------------------------------------------
__global__ __launch_bounds__(256) void gemm_kernel(
    const float* __restrict__ x,
    const float* __restrict__ Wf, const float* __restrict__ Wi,
    const float* __restrict__ Wu, const float* __restrict__ Wo,
    const float* __restrict__ bf, const float* __restrict__ bi,
    const float* __restrict__ bu, const float* __restrict__ bo,
    float* __restrict__ A) {
  __shared__ float4 xs[DIN / 4];
  const int t   = blockIdx.x;
  const int tid = threadIdx.x;

  const float4* xrow = (const float4*)(x + (size_t)t * DIN);
  xs[tid]       = xrow[tid];
  xs[tid + 256] = xrow[tid + 256];
  __syncthreads();

  const int wave = tid >> 6;
  const int lane = tid & 63;
  const float* W  = (wave == 0) ? Wf : (wave == 1) ? Wi : (wave == 2) ? Wu : Wo;
  const float* bg = (wave == 0) ? bf : (wave == 1) ? bi : (wave == 2) ? bu : bo;

  for (int q = 0; q < QG; ++q) {
    const float4* wrow = (const float4*)(W + (size_t)q * DTOT);
    float acc = 0.f;
#pragma unroll
    for (int j = 0; j < 8; ++j) {
      float4 w4 = wrow[lane + 64 * j];
      float4 x4 = xs[lane + 64 * j];
      acc = fmaf(w4.x, x4.x, acc);
      acc = fmaf(w4.y, x4.y, acc);
      acc = fmaf(w4.z, x4.z, acc);
      acc = fmaf(w4.w, x4.w, acc);
    }
#pragma unroll
    for (int off = 32; off > 0; off >>= 1) acc += __shfl_xor(acc, off);
    if (lane == 0) A[(size_t)t * NQQ + wave * QG + q] = (acc + bg[q]) * INV4PI;
  }
}

// ---------------------------------------------------------------------------
// Kernel 2: S[qq] = sum_d W_gate[q, DIN + d] * INV4PI   (hidden-part row sums)
// ---------------------------------------------------------------------------
__global__ __launch_bounds__(64) void rowsum_kernel(
    const float* __restrict__ Wf, const float* __restrict__ Wi,
    const float* __restrict__ Wu, const float* __restrict__ Wo,
    float* __restrict__ S) {
  const int b    = blockIdx.x;
  const int gate = b >> 3;
  const int q    = b & 7;
  const int lane = threadIdx.x;
  const float* W = (gate == 0) ? Wf : (gate == 1) ? Wi : (gate == 2) ? Wu : Wo;
  const float4* row = (const float4*)(W + (size_t)q * DTOT + DIN);
  float acc = 0.f;
#pragma unroll
  for (int j = 0; j < 8; ++j) {
    float4 w4 = row[lane + 64 * j];
    acc += w4.x + w4.y + w4.z + w4.w;
  }
#pragma unroll
  for (int off = 32; off > 0; off >>= 1) acc += __shfl_xor(acc, off);
  if (lane == 0) S[b] = acc * INV4PI;
}

// ---------------------------------------------------------------------------
// Kernel 3: the serial scan. One wave; lane (&15) = L owns gate L>>2's two
// angles {2L, 2L+1}. Per-lane partial (c1*c2)^2, quad_perm xor1+xor2
// (involutions) -> quad g holds P_g. readlane 0/4/8/12 -> scalar gates.
// 8-deep register prefetch pipeline on A (~880 cy in flight) hides HBM/L2
// latency; h*S folded as th*(o*S) so the o-mul overlaps the tanh chain.
// ---------------------------------------------------------------------------
__global__ __launch_bounds__(64) void scan_kernel(
    const float* __restrict__ A, const float* __restrict__ S,
    float* __restrict__ hbuf, float* __restrict__ cfin) {
  const int lane = threadIdx.x;
  const int li   = lane & 15;               // all 64 lanes mirror the 16 active
  const float2* A2 = (const float2*)A;      // A2[t*16 + L] = angles {2L,2L+1}
  const float2* S2 = (const float2*)S;
  const float2 Sv = S2[li];
  const bool isTanh = (li >= 8 && li < 12);
  // gate = a1 * rcp(1 + exp2(fma(P, ka, kb))) + a2
  const float ka = isTanh ? (-4.f * L2E) : (-2.f * L2E);
  const float kb = isTanh ? (2.f * L2E) : (L2E);
  const float a1 = isTanh ? 2.f : 1.f;
  const float a2 = isTanh ? -1.f : 0.f;

  float c  = 0.f;
  float th = 0.f;                 // tanh(c) carried across steps
  float qx = 0.f, qy = 0.f;       // o * Sv, carried across steps (h*S = th*q)
  float o_prev = 0.f;             // for the h store (off critical path)

  float2 buf[8];
#pragma unroll
  for (int j = 0; j < 8; ++j) buf[j] = A2[(size_t)j * 16 + li];

  for (int t0 = 0; t0 < T_STEPS; t0 += 8) {
#pragma unroll
    for (int j = 0; j < 8; ++j) {
      const float2 Acur = buf[j];
      int tp = t0 + j + 8;
      if (tp > T_STEPS - 1) tp = T_STEPS - 1;
      buf[j] = A2[(size_t)tp * 16 + li];     // refill: consumed 8 steps later

      const float ang1 = fmaf(th, qx, Acur.x);   // = h*Sv.x + A
      const float ang2 = fmaf(th, qy, Acur.y);
      const float c1 = COS_REV(ang1);            // parallel transcendentals
      const float c2 = COS_REV(ang2);
      float p = c1 * c2;
      p = p * p;                                 // cos^2(a)*cos^2(b)
      p = DPP_MUL(p, 0xB1);                      // quad_perm xor 1
      p = DPP_MUL(p, 0x4E);                      // quad_perm xor 2

      const float e  = EXP2F(fmaf(p, ka, kb));
      const float r  = RCPF(1.f + e);
      const float gv = fmaf(a1, r, a2);          // sigma(2P-1) or tanh(2P-1)

      const float f_ = READLANE_F(gv, 0);
      const float i_ = READLANE_F(gv, 4);
      const float g_ = READLANE_F(gv, 8);
      const float o_ = READLANE_F(gv, 12);

      qx = o_ * Sv.x;                            // overlaps the tanh chain
      qy = o_ * Sv.y;

      c = fmaf(f_, c, i_ * g_);
      const float e2 = EXP2F(c * (-2.f * L2E));
      th = fmaf(2.f, RCPF(1.f + e2), -1.f);      // tanh(c)

      if (lane == 0) hbuf[t0 + j] = o_ * th;     // h, off critical path
      o_prev = o_;
      (void)o_prev;
    }
  }
  if (lane == 0) cfin[0] = c;
}

// ---------------------------------------------------------------------------
// Kernel 4: broadcast h_t over DH, plus hx / cx tails.
// ---------------------------------------------------------------------------
__global__ __launch_bounds__(256) void bcast_kernel(
    const float* __restrict__ hbuf, const float* __restrict__ cfin,
    float* __restrict__ out) {
  const int b = blockIdx.x;
  float v;
  size_t off;
  if (b < T_STEPS) {
    v = hbuf[b];
    off = (size_t)b * DH;
  } else if (b == T_STEPS) {
    v = hbuf[T_STEPS - 1];
    off = (size_t)T_STEPS * DH;
  } else {
    v = cfin[0];
    off = (size_t)T_STEPS * DH + DH;
  }
  const float4 v4 = make_float4(v, v, v, v);
  float4* dst = (float4*)(out + off);
  dst[threadIdx.x]       = v4;
  dst[threadIdx.x + 256] = v4;
}

extern "C" void kernel_launch(void* const* d_in, const int* in_sizes, int n_in,
                              void* d_out, int out_size, void* d_ws, size_t ws_size,
                              hipStream_t stream) {
  const float* x  = (const float*)d_in[0];
  const float* Wf = (const float*)d_in[1];
  const float* bf = (const float*)d_in[2];
  const float* Wi = (const float*)d_in[3];
  const float* bi = (const float*)d_in[4];
  const float* Wu = (const float*)d_in[5];
  const float* bu = (const float*)d_in[6];
  const float* Wo = (const float*)d_in[7];
  const float* bo = (const float*)d_in[8];
  float* out = (float*)d_out;

  // workspace layout (floats): A[8192*32] | S[32] | hbuf[8192] | cfin[1]
  float* A    = (float*)d_ws;
  float* S    = A + (size_t)T_STEPS * NQQ;
  float* hbuf = S + NQQ;
  float* cfin = hbuf + T_STEPS;

  hipLaunchKernelGGL(gemm_kernel, dim3(T_STEPS), dim3(256), 0, stream,
                     x, Wf, Wi, Wu, Wo, bf, bi, bu, bo, A);
  hipLaunchKernelGGL(rowsum_kernel, dim3(NQQ), dim3(64), 0, stream,
                     Wf, Wi, Wu, Wo, S);
  hipLaunchKernelGGL(scan_kernel, dim3(1), dim3(64), 0, stream,
                     A, S, hbuf, cfin);
  hipLaunchKernelGGL(bcast_kernel, dim3(T_STEPS + 2), dim3(256), 0, stream,
                     hbuf, cfin, out);
}